// Round 5
// baseline (14.000 us; speedup 1.0000x reference)
//
#include <hip/hip_runtime.h>

#define N_ATT    2048
#define B_ROWS   32
#define THREADS  256
#define R_I      8                         // i-values per thread (full row / 256)
#define JCHUNK   64
#define JSPLITS  (N_ATT / JCHUNK)          // 32
#define NBLOCKS  (B_ROWS * JSPLITS)        // 1024
#define C_CLS    10
#define BETA     0.5f
#define EPS_ATT  1e-6f

// Kernel 1: per-(row, j-chunk) partial Gini sums.
// 1024 blocks (4/CU, 4 waves/SIMD). Each thread holds 8 register-resident
// xi spanning the whole row; each uniform-address ds_read_b128 feeds
// 8 i x 4 j x 2 = 64 VALU ops, with 8 independent accumulator chains.
__global__ __launch_bounds__(THREADS)
void gini_partial(const float* __restrict__ att, float* __restrict__ ws) {
    __shared__ float xs[JCHUNK];
    const int b      = blockIdx.x;
    const int row    = b >> 5;             // 32 j-blocks per row
    const int jsplit = b & 31;             // 0..31
    const int t      = threadIdx.x;
    const float* a   = att + row * N_ATT;

    // stage j-chunk (64 floats) into LDS as log(att+eps)
    if (t < JCHUNK) xs[t] = logf(a[jsplit * JCHUNK + t] + EPS_ATT);

    // 8 register-resident xi per thread (coalesced loads, cover full row)
    float xi[R_I];
#pragma unroll
    for (int k = 0; k < R_I; ++k)
        xi[k] = logf(a[k * THREADS + t] + EPS_ATT);
    __syncthreads();

    float acc[R_I];
#pragma unroll
    for (int k = 0; k < R_I; ++k) acc[k] = 0.f;

    const float4* xs4 = reinterpret_cast<const float4*>(xs);
#pragma unroll
    for (int j = 0; j < JCHUNK / 4; ++j) {
        const float4 v = xs4[j];
#pragma unroll
        for (int k = 0; k < R_I; ++k) {
            acc[k] += fabsf(xi[k] - v.x);
            acc[k] += fabsf(xi[k] - v.y);
            acc[k] += fabsf(xi[k] - v.z);
            acc[k] += fabsf(xi[k] - v.w);
        }
    }
    float s = ((acc[0] + acc[1]) + (acc[2] + acc[3]))
            + ((acc[4] + acc[5]) + (acc[6] + acc[7]));

    // block reduce (wave = 64)
#pragma unroll
    for (int off = 32; off > 0; off >>= 1) s += __shfl_down(s, off);
    __shared__ float wsum[THREADS / 64];
    const int lane = t & 63, wid = t >> 6;
    if (lane == 0) wsum[wid] = s;
    __syncthreads();
    if (t == 0) {
        float tot = 0.f;
#pragma unroll
        for (int w = 0; w < THREADS / 64; ++w) tot += wsum[w];
        ws[b] = tot;
    }
}

// Kernel 2: cross-entropy + combine. One block of 256 threads.
__global__ __launch_bounds__(THREADS)
void finalize(const float* __restrict__ logits, const int* __restrict__ labels,
              const float* __restrict__ ws, float* __restrict__ out) {
    const int t = threadIdx.x;

    float ce = 0.f;
    if (t < B_ROWS) {
        const float* lg = logits + t * C_CLS;
        float m = lg[0];
#pragma unroll
        for (int c = 1; c < C_CLS; ++c) m = fmaxf(m, lg[c]);
        float sum = 0.f;
#pragma unroll
        for (int c = 0; c < C_CLS; ++c) sum += expf(lg[c] - m);
        ce = m + logf(sum) - lg[labels[t]];   // -log_softmax[label]
    }

    // 1024 partials, 4 per thread (fixed order -> deterministic)
    float g = ws[t] + ws[t + 256] + ws[t + 512] + ws[t + 768];

    float cs = ce, gs = g;
#pragma unroll
    for (int off = 32; off > 0; off >>= 1) {
        cs += __shfl_down(cs, off);
        gs += __shfl_down(gs, off);
    }
    __shared__ float sc[THREADS / 64], sg[THREADS / 64];
    const int lane = t & 63, wid = t >> 6;
    if (lane == 0) { sc[wid] = cs; sg[wid] = gs; }
    __syncthreads();
    if (t == 0) {
        float ce_tot = 0.f, g_tot = 0.f;
#pragma unroll
        for (int w = 0; w < THREADS / 64; ++w) { ce_tot += sc[w]; g_tot += sg[w]; }
        const float pred = ce_tot / (float)B_ROWS;
        const float info = g_tot / (2.0f * (float)N_ATT * (float)N_ATT + 1e-9f);
        out[0] = pred - BETA * info;
    }
}

extern "C" void kernel_launch(void* const* d_in, const int* in_sizes, int n_in,
                              void* d_out, int out_size, void* d_ws, size_t ws_size,
                              hipStream_t stream) {
    const float* att    = (const float*)d_in[0];   // [32, 2048] f32
    const float* logits = (const float*)d_in[1];   // [32, 10]   f32
    const int*   labels = (const int*)d_in[2];     // [32]       i32
    float* out = (float*)d_out;                    // scalar f32
    float* ws  = (float*)d_ws;                     // 1024 floats of scratch

    gini_partial<<<NBLOCKS, THREADS, 0, stream>>>(att, ws);
    finalize<<<1, THREADS, 0, stream>>>(logits, labels, ws, out);
}

// Round 6
// 12.390 us; speedup vs baseline: 1.1300x; 1.1300x over previous
//
#include <hip/hip_runtime.h>

#define N_ATT    2048
#define B_ROWS   32
#define THREADS  256
#define CHUNK    256
#define NCHUNK   (N_ATT / CHUNK)            // 8
#define NTILES   (NCHUNK * (NCHUNK + 1) / 2) // 36 tiles (a<=b) per row
#define GBLOCKS  (B_ROWS * NTILES)          // 1152 gini blocks
#define NBLOCKS  (GBLOCKS + 1)              // +1 CE block
#define C_CLS    10
#define BETA     0.5f
#define EPS_ATT  1e-6f

// upper-triangle tile decode tables (a<=b), 36 entries
static __device__ const unsigned char TA[NTILES] = {
    0,0,0,0,0,0,0,0, 1,1,1,1,1,1,1, 2,2,2,2,2,2, 3,3,3,3,3, 4,4,4,4, 5,5,5, 6,6, 7};
static __device__ const unsigned char TB[NTILES] = {
    0,1,2,3,4,5,6,7, 1,2,3,4,5,6,7, 2,3,4,5,6,7, 3,4,5,6,7, 4,5,6,7, 5,6,7, 6,7, 7};

// Kernel 1: symmetric-tile partial Gini + (one block) cross-entropy.
// S_row = sum_a S_aa + 2*sum_{a<b} S_ab, S_ab = full ordered-pair sum of
// the 256x256 tile. Each thread: 1 register xi vs 256 LDS j's (4 acc chains).
__global__ __launch_bounds__(THREADS)
void gini_ce(const float* __restrict__ att, const float* __restrict__ logits,
             const int* __restrict__ labels, float* __restrict__ ws) {
    const int b = blockIdx.x;
    const int t = threadIdx.x;

    if (b == GBLOCKS) {                    // dedicated CE block (concurrent, short)
        float ce = 0.f;
        if (t < B_ROWS) {
            const float* lg = logits + t * C_CLS;
            float m = lg[0];
#pragma unroll
            for (int c = 1; c < C_CLS; ++c) m = fmaxf(m, lg[c]);
            float sum = 0.f;
#pragma unroll
            for (int c = 0; c < C_CLS; ++c) sum += expf(lg[c] - m);
            ce = m + logf(sum) - lg[labels[t]];
        }
        // rows 0..31 live in wave 0; reduce within that wave
#pragma unroll
        for (int off = 16; off > 0; off >>= 1) ce += __shfl_down(ce, off);
        if (t == 0) ws[GBLOCKS] = ce;      // sum of CE over batch
        return;
    }

    const int row  = b / NTILES;
    const int tidx = b - row * NTILES;
    const int ca   = TA[tidx], cb = TB[tidx];
    const float* a = att + row * N_ATT;

    __shared__ float xb[CHUNK];
    xb[t] = logf(a[cb * CHUNK + t] + EPS_ATT);           // stage j-chunk (log'd)
    const float xi = logf(a[ca * CHUNK + t] + EPS_ATT);  // register i-value
    __syncthreads();

    float s0 = 0.f, s1 = 0.f, s2 = 0.f, s3 = 0.f;        // 4 independent chains
    const float4* xb4 = reinterpret_cast<const float4*>(xb);
#pragma unroll
    for (int j = 0; j < CHUNK / 4; ++j) {
        const float4 v = xb4[j];
        s0 += fabsf(xi - v.x);
        s1 += fabsf(xi - v.y);
        s2 += fabsf(xi - v.z);
        s3 += fabsf(xi - v.w);
    }
    float s = (s0 + s1) + (s2 + s3);

    // block reduce (wave = 64)
#pragma unroll
    for (int off = 32; off > 0; off >>= 1) s += __shfl_down(s, off);
    __shared__ float wsum[THREADS / 64];
    const int lane = t & 63, wid = t >> 6;
    if (lane == 0) wsum[wid] = s;
    __syncthreads();
    if (t == 0) {
        float tot = 0.f;
#pragma unroll
        for (int w = 0; w < THREADS / 64; ++w) tot += wsum[w];
        ws[b] = (ca == cb) ? tot : 2.0f * tot;           // symmetry weight
    }
}

// Kernel 2: pure deterministic sum of 1152 gini partials + ce, final combine.
__global__ __launch_bounds__(THREADS)
void finalize(const float* __restrict__ ws, float* __restrict__ out) {
    const int t = threadIdx.x;

    float g = 0.f;
#pragma unroll
    for (int k = 0; k < 5; ++k) {          // covers 0..1279, mask to 1152
        const int idx = t + k * THREADS;
        if (idx < GBLOCKS) g += ws[idx];
    }

#pragma unroll
    for (int off = 32; off > 0; off >>= 1) g += __shfl_down(g, off);
    __shared__ float sg[THREADS / 64];
    const int lane = t & 63, wid = t >> 6;
    if (lane == 0) sg[wid] = g;
    __syncthreads();
    if (t == 0) {
        float g_tot = 0.f;
#pragma unroll
        for (int w = 0; w < THREADS / 64; ++w) g_tot += sg[w];
        const float pred = ws[GBLOCKS] / (float)B_ROWS;  // CE sum -> mean
        const float info = g_tot / (2.0f * (float)N_ATT * (float)N_ATT + 1e-9f);
        out[0] = pred - BETA * info;
    }
}

extern "C" void kernel_launch(void* const* d_in, const int* in_sizes, int n_in,
                              void* d_out, int out_size, void* d_ws, size_t ws_size,
                              hipStream_t stream) {
    const float* att    = (const float*)d_in[0];   // [32, 2048] f32
    const float* logits = (const float*)d_in[1];   // [32, 10]   f32
    const int*   labels = (const int*)d_in[2];     // [32]       i32
    float* out = (float*)d_out;                    // scalar f32
    float* ws  = (float*)d_ws;                     // 1153 floats of scratch

    gini_ce<<<NBLOCKS, THREADS, 0, stream>>>(att, logits, labels, ws);
    finalize<<<1, THREADS, 0, stream>>>(ws, out);
}

// Round 8
// 12.344 us; speedup vs baseline: 1.1342x; 1.0038x over previous
//
#include <hip/hip_runtime.h>

#define N_ATT    2048
#define B_ROWS   32
#define THREADS  256
#define CHUNK    256
#define NCHUNK   (N_ATT / CHUNK)             // 8
#define NTILES   (NCHUNK * (NCHUNK + 1) / 2) // 36 tiles (a<=b) per row
#define GBLOCKS  (B_ROWS * NTILES)           // 1152 gini blocks
#define NBLOCKS  (GBLOCKS + 1)               // +1 CE block
#define C_CLS    10
#define BETA     0.5f
#define EPS_ATT  1e-6f

// upper-triangle tile decode tables (a<=b), 36 entries
static __device__ const unsigned char TA[NTILES] = {
    0,0,0,0,0,0,0,0, 1,1,1,1,1,1,1, 2,2,2,2,2,2, 3,3,3,3,3, 4,4,4,4, 5,5,5, 6,6, 7};
static __device__ const unsigned char TB[NTILES] = {
    0,1,2,3,4,5,6,7, 1,2,3,4,5,6,7, 2,3,4,5,6,7, 3,4,5,6,7, 4,5,6,7, 5,6,7, 6,7, 7};

// Kernel 1: symmetric-tile partial Gini + (one block) cross-entropy.
// S_row = sum_a S_aa + 2*sum_{a<b} S_ab; each thread: 1 register xi vs 256
// LDS j's, 4 independent accumulator chains; 2 VALU/pair (sub + add-abs).
__global__ __launch_bounds__(THREADS)
void gini_ce(const float* __restrict__ att, const float* __restrict__ logits,
             const int* __restrict__ labels, float* __restrict__ ws) {
    const int b = blockIdx.x;
    const int t = threadIdx.x;

    if (b == GBLOCKS) {                    // dedicated CE block (concurrent, short)
        float ce = 0.f;
        if (t < B_ROWS) {
            const float* lg = logits + t * C_CLS;
            float m = lg[0];
#pragma unroll
            for (int c = 1; c < C_CLS; ++c) m = fmaxf(m, lg[c]);
            float sum = 0.f;
#pragma unroll
            for (int c = 0; c < C_CLS; ++c) sum += expf(lg[c] - m);
            ce = m + logf(sum) - lg[labels[t]];
        }
#pragma unroll
        for (int off = 16; off > 0; off >>= 1) ce += __shfl_down(ce, off);
        if (t == 0) ws[GBLOCKS] = ce;      // sum of CE over batch
        return;
    }

    const int row  = b / NTILES;
    const int tidx = b - row * NTILES;
    const int ca   = TA[tidx], cb = TB[tidx];
    const float* a = att + row * N_ATT;

    __shared__ float xb[CHUNK];
    xb[t] = logf(a[cb * CHUNK + t] + EPS_ATT);           // stage j-chunk (log'd)
    const float xi = logf(a[ca * CHUNK + t] + EPS_ATT);  // register i-value
    __syncthreads();

    float s0 = 0.f, s1 = 0.f, s2 = 0.f, s3 = 0.f;        // 4 independent chains
    const float4* xb4 = reinterpret_cast<const float4*>(xb);
#pragma unroll
    for (int j = 0; j < CHUNK / 4; ++j) {
        const float4 v = xb4[j];                         // ds_read_b128 broadcast
        s0 += fabsf(xi - v.x);
        s1 += fabsf(xi - v.y);
        s2 += fabsf(xi - v.z);
        s3 += fabsf(xi - v.w);
    }
    float s = (s0 + s1) + (s2 + s3);

    // block reduce (wave = 64)
#pragma unroll
    for (int off = 32; off > 0; off >>= 1) s += __shfl_down(s, off);
    __shared__ float wsum[THREADS / 64];
    const int lane = t & 63, wid = t >> 6;
    if (lane == 0) wsum[wid] = s;
    __syncthreads();
    if (t == 0) {
        float tot = 0.f;
#pragma unroll
        for (int w = 0; w < THREADS / 64; ++w) tot += wsum[w];
        ws[b] = (ca == cb) ? tot : 2.0f * tot;           // symmetry weight
    }
}

// Kernel 2: pure deterministic sum of 1152 gini partials + ce, final combine.
__global__ __launch_bounds__(THREADS)
void finalize(const float* __restrict__ ws, float* __restrict__ out) {
    const int t = threadIdx.x;

    float g = 0.f;
#pragma unroll
    for (int k = 0; k < 5; ++k) {          // covers 0..1279, mask to 1152
        const int idx = t + k * THREADS;
        if (idx < GBLOCKS) g += ws[idx];
    }

#pragma unroll
    for (int off = 32; off > 0; off >>= 1) g += __shfl_down(g, off);
    __shared__ float sg[THREADS / 64];
    const int lane = t & 63, wid = t >> 6;
    if (lane == 0) sg[wid] = g;
    __syncthreads();
    if (t == 0) {
        float g_tot = 0.f;
#pragma unroll
        for (int w = 0; w < THREADS / 64; ++w) g_tot += sg[w];
        const float pred = ws[GBLOCKS] / (float)B_ROWS;  // CE sum -> mean
        const float info = g_tot / (2.0f * (float)N_ATT * (float)N_ATT + 1e-9f);
        out[0] = pred - BETA * info;
    }
}

extern "C" void kernel_launch(void* const* d_in, const int* in_sizes, int n_in,
                              void* d_out, int out_size, void* d_ws, size_t ws_size,
                              hipStream_t stream) {
    const float* att    = (const float*)d_in[0];   // [32, 2048] f32
    const float* logits = (const float*)d_in[1];   // [32, 10]   f32
    const int*   labels = (const int*)d_in[2];     // [32]       i32
    float* out = (float*)d_out;                    // scalar f32
    float* ws  = (float*)d_ws;                     // 1153 floats of scratch

    gini_ce<<<NBLOCKS, THREADS, 0, stream>>>(att, logits, labels, ws);
    finalize<<<1, THREADS, 0, stream>>>(ws, out);
}